// Round 1
// baseline (541.078 us; speedup 1.0000x reference)
//
#include <hip/hip_runtime.h>

// Encoder_29661044146233 — round 1: correct fp32 baseline.
// Pipeline: conv1(2048->1024) -> graph1 (in-place) -> conv2(1024->512) ->
//           graph2 (in-place) -> conv3(512->256, writes only pos channels).
// Activations packed (B, F, 88) fp32, channel = joint*4 + c (c=3 is edge/offset).

static constexpr int Jn = 22;
static constexpr int C4 = 88;     // 22 joints * 4 channels
__device__ constexpr int TOPc[Jn] = {0,0,1,2,3,4,0,6,7,8,0,10,11,12,12,14,15,16,12,18,19,20};

// ---------------- conv1d: kernel 4, stride 2, pad (1,1) ----------------
// y[b,fo,co] = bias[co] + sum_{ci,k} w[co,ci,k] * x[b, 2*fo-1+k, ci]
// MODE 0: inputs are (input (B,F,22,3), offset (B,F,22,1)) gathered on the fly
// MODE 1: input is packed (B,F,88)
// MODE 2: like 1, but output written as (B,F,22,3) keeping only c<3
template<int FIN, int MODE>
__global__ __launch_bounds__(128)
void conv_kernel(const float* __restrict__ xin, const float* __restrict__ xoff,
                 const float* __restrict__ w, const float* __restrict__ bias,
                 float* __restrict__ yout)
{
    constexpr int FOUT = FIN / 2;
    constexpr int TF   = 16;          // output frames per block
    constexpr int NFR  = 2 * TF + 2;  // input frames needed = 34
    constexpr int FSTR = 36;          // padded frame stride (16B-aligned float4 reads)

    __shared__ float Xs[C4][FSTR];    // transposed tile: [channel][frame]

    constexpr int NTILE = FOUT / TF;
    const int b   = blockIdx.x / NTILE;
    const int fo0 = (blockIdx.x - b * NTILE) * TF;
    const int tid = threadIdx.x;
    const int gf0 = 2 * fo0 - 1;

    // ---- stage input tile into LDS (transposed) ----
    for (int idx = tid; idx < NFR * C4; idx += 128) {
        const int lf = idx / C4;
        const int ci = idx - lf * C4;
        const int gf = gf0 + lf;
        float v = 0.f;
        if (gf >= 0 && gf < FIN) {
            if (MODE == 0) {
                const int j = ci >> 2, c = ci & 3;
                if (c < 3) v = xin[((b * FIN + gf) * Jn + j) * 3 + c];
                else       v = xoff[(b * FIN + gf) * Jn + j];
            } else {
                v = xin[(b * FIN + gf) * C4 + ci];
            }
        }
        Xs[ci][lf] = v;
    }
    __syncthreads();

    const int co = tid;
    if (co >= C4) return;             // 88 of 128 lanes active

    float acc[TF];
#pragma unroll
    for (int i = 0; i < TF; ++i) acc[i] = 0.f;

    // weight row for this output channel: w[co][ci][0..3] is a contiguous float4
    const float4* wrow = reinterpret_cast<const float4*>(w) + co * C4;

#pragma unroll 2
    for (int ci = 0; ci < C4; ++ci) {
        const float4 w4 = wrow[ci];
        float xv[FSTR];
#pragma unroll
        for (int q = 0; q < FSTR / 4; ++q) {
            const float4 t = *reinterpret_cast<const float4*>(&Xs[ci][4 * q]);
            xv[4 * q + 0] = t.x; xv[4 * q + 1] = t.y;
            xv[4 * q + 2] = t.z; xv[4 * q + 3] = t.w;
        }
#pragma unroll
        for (int fo = 0; fo < TF; ++fo) {
            acc[fo] += w4.x * xv[2 * fo + 0];
            acc[fo] += w4.y * xv[2 * fo + 1];
            acc[fo] += w4.z * xv[2 * fo + 2];
            acc[fo] += w4.w * xv[2 * fo + 3];
        }
    }

    const float bi = bias[co];
    if (MODE < 2) {
#pragma unroll
        for (int fo = 0; fo < TF; ++fo)
            yout[(b * FOUT + fo0 + fo) * C4 + co] = acc[fo] + bi;
    } else {
        const int j = co >> 2, c = co & 3;
        if (c < 3) {
#pragma unroll
            for (int fo = 0; fo < TF; ++fo)
                yout[((b * FOUT + fo0 + fo) * Jn + j) * 3 + c] = acc[fo] + bi;
        }
    }
}

// ---------------- graph block (per (b,f) row, in-place safe) ----------------
struct GW {
    const float *n2n_w, *n2n_b, *e2n_we, *e2n_wn, *e2n_b;
    const float *n2e_wn, *n2e_we, *n2e_b, *lin_w, *lin_b;
};

__global__ __launch_bounds__(256)
void graph_kernel(const float* x, float* y, GW g, int nrow)
{
    const int row = blockIdx.x * 256 + threadIdx.x;
    if (row >= nrow) return;

    const float4* xr = reinterpret_cast<const float4*>(x) + row * Jn;
    float4*       yr = reinterpret_cast<float4*>(y) + row * Jn;

    float nd[Jn][3], ed[Jn];
#pragma unroll
    for (int j = 0; j < Jn; ++j) {
        const float4 t = xr[j];
        nd[j][0] = t.x; nd[j][1] = t.y; nd[j][2] = t.z; ed[j] = t.w;
    }

    // small weights (wave-uniform addresses -> scalar loads)
    float n2n[9], n2nb[3], e2we[3], e2wn[9], e2nb[3], newn[3], lin[18], linb[3];
#pragma unroll
    for (int i = 0; i < 9;  ++i) n2n[i]  = g.n2n_w[i];
#pragma unroll
    for (int i = 0; i < 3;  ++i) n2nb[i] = g.n2n_b[i];
#pragma unroll
    for (int i = 0; i < 3;  ++i) e2we[i] = g.e2n_we[i];
#pragma unroll
    for (int i = 0; i < 9;  ++i) e2wn[i] = g.e2n_wn[i];
#pragma unroll
    for (int i = 0; i < 3;  ++i) e2nb[i] = g.e2n_b[i];
#pragma unroll
    for (int i = 0; i < 3;  ++i) newn[i] = g.n2e_wn[i];
    const float newe = g.n2e_we[0];
    const float neb  = g.n2e_b[0];
#pragma unroll
    for (int i = 0; i < 18; ++i) lin[i]  = g.lin_w[i];
#pragma unroll
    for (int i = 0; i < 3;  ++i) linb[i] = g.lin_b[i];

#pragma unroll
    for (int i = 0; i < Jn; ++i) {
        // child aggregation (compile-time children lists)
        float an0 = 0.f, an1 = 0.f, an2 = 0.f, ae = 0.f;
#pragma unroll
        for (int j = 1; j < Jn; ++j) {
            if (TOPc[j] == i) {
                an0 += nd[j][0]; an1 += nd[j][1]; an2 += nd[j][2]; ae += ed[j];
            }
        }
        float f1[3], f2[3];
#pragma unroll
        for (int c = 0; c < 3; ++c) {
            f1[c] = an0 * n2n[0 * 3 + c] + an1 * n2n[1 * 3 + c] + an2 * n2n[2 * 3 + c] + n2nb[c];
            f2[c] = ae * e2we[c]
                  + nd[i][0] * e2wn[0 * 3 + c] + nd[i][1] * e2wn[1 * 3 + c] + nd[i][2] * e2wn[2 * 3 + c]
                  + e2nb[c];
        }
        float p0 = 0.f, p1 = 0.f, p2 = 0.f;
        if (i > 0) { const int p = TOPc[i]; p0 = nd[p][0]; p1 = nd[p][1]; p2 = nd[p][2]; }
        const float ne = p0 * newn[0] + p1 * newn[1] + p2 * newn[2] + ed[i] * newe + neb;

        float4 o;
        o.x = f1[0] * lin[0 * 3 + 0] + f1[1] * lin[1 * 3 + 0] + f1[2] * lin[2 * 3 + 0]
            + f2[0] * lin[3 * 3 + 0] + f2[1] * lin[4 * 3 + 0] + f2[2] * lin[5 * 3 + 0] + linb[0];
        o.y = f1[0] * lin[0 * 3 + 1] + f1[1] * lin[1 * 3 + 1] + f1[2] * lin[2 * 3 + 1]
            + f2[0] * lin[3 * 3 + 1] + f2[1] * lin[4 * 3 + 1] + f2[2] * lin[5 * 3 + 1] + linb[1];
        o.z = f1[0] * lin[0 * 3 + 2] + f1[1] * lin[1 * 3 + 2] + f1[2] * lin[2 * 3 + 2]
            + f2[0] * lin[3 * 3 + 2] + f2[1] * lin[4 * 3 + 2] + f2[2] * lin[5 * 3 + 2] + linb[2];
        o.w = ne;
        yr[i] = o;
    }
}

extern "C" void kernel_launch(void* const* d_in, const int* in_sizes, int n_in,
                              void* d_out, int out_size, void* d_ws, size_t ws_size,
                              hipStream_t stream)
{
    (void)n_in; (void)out_size; (void)ws_size;

    const float* input  = (const float*)d_in[0];
    const float* offset = (const float*)d_in[1];
    const float* c1w = (const float*)d_in[2]; const float* c1b = (const float*)d_in[3];
    const float* c2w = (const float*)d_in[4]; const float* c2b = (const float*)d_in[5];
    const float* c3w = (const float*)d_in[6]; const float* c3b = (const float*)d_in[7];

    GW g1 { (const float*)d_in[8],  (const float*)d_in[9],  (const float*)d_in[10],
            (const float*)d_in[11], (const float*)d_in[12], (const float*)d_in[13],
            (const float*)d_in[14], (const float*)d_in[15], (const float*)d_in[16],
            (const float*)d_in[17] };
    GW g2 { (const float*)d_in[18], (const float*)d_in[19], (const float*)d_in[20],
            (const float*)d_in[21], (const float*)d_in[22], (const float*)d_in[23],
            (const float*)d_in[24], (const float*)d_in[25], (const float*)d_in[26],
            (const float*)d_in[27] };

    const int B = in_sizes[0] / (2048 * Jn * 3);   // 128

    float* ws1 = (float*)d_ws;                         // (B,1024,88) = 46.1 MB
    float* ws2 = ws1 + (size_t)B * 1024 * C4;          // (B, 512,88) = 23.1 MB
    float* out = (float*)d_out;                        // (B, 256,22,3)

    // conv1: (B,2048) -> (B,1024,88)
    conv_kernel<2048, 0><<<B * (1024 / 16), 128, 0, stream>>>(input, offset, c1w, c1b, ws1);
    // graph1 in-place
    graph_kernel<<<(B * 1024 + 255) / 256, 256, 0, stream>>>(ws1, ws1, g1, B * 1024);
    // conv2: -> (B,512,88)
    conv_kernel<1024, 1><<<B * (512 / 16), 128, 0, stream>>>(ws1, nullptr, c2w, c2b, ws2);
    // graph2 in-place
    graph_kernel<<<(B * 512 + 255) / 256, 256, 0, stream>>>(ws2, ws2, g2, B * 512);
    // conv3: -> d_out (B,256,22,3), pos channels only
    conv_kernel<512, 2><<<B * (256 / 16), 128, 0, stream>>>(ws2, nullptr, c3w, c3b, out);
}

// Round 2
// 183.876 us; speedup vs baseline: 2.9426x; 2.9426x over previous
//
#include <hip/hip_runtime.h>

// Encoder_29661044146233 — round 2: bf16 MFMA convs (implicit GEMM), fp32 graph blocks.
// conv as GEMM: M = output frames, N = 88 out-channels (pad 96), K = 352 (= 88 ci * 4 taps).
// X-tile staged transposed [ci][frame] bf16 in LDS (row stride 524 B = odd word count ->
// conflict-free staging writes and A-frag reads). Weights pre-cast to bf16 [co][kk] in ws.

static constexpr int Jn   = 22;
static constexpr int C4   = 88;     // 22 joints * 4 channels
static constexpr int KK   = 352;    // C4 * 4 taps
static constexpr int NPAD = 96;     // padded N (6 tiles of 16)
static constexpr int RSB  = 524;    // LDS X-tile row stride in bytes (131 words, odd)

typedef __attribute__((ext_vector_type(8))) short  short8;
typedef __attribute__((ext_vector_type(4))) float  floatx4;

__device__ constexpr int TOPc[Jn] = {0,0,1,2,3,4,0,6,7,8,0,10,11,12,12,14,15,16,12,18,19,20};

__device__ __forceinline__ unsigned short f2bf(float f) {
    unsigned u = __builtin_bit_cast(unsigned, f);
    unsigned r = (u + 0x7FFFu + ((u >> 16) & 1u)) >> 16;
    return (unsigned short)r;
}

// ---- pre-pass: cast conv weights fp32 (88,88,4) -> bf16 [96][352], zero-padded rows ----
__global__ __launch_bounds__(256)
void prep_weights(const float* __restrict__ w1, const float* __restrict__ w2,
                  const float* __restrict__ w3, unsigned short* __restrict__ o)
{
    const int i = blockIdx.x * 256 + threadIdx.x;
    constexpr int per = NPAD * KK;
    if (i >= 3 * per) return;
    const int s  = i / per, r = i - s * per;
    const int co = r / KK;
    const float* w = (s == 0) ? w1 : (s == 1) ? w2 : w3;
    float v = (co < C4) ? w[r - (co - 0) * KK + co * KK - co * KK + (co * KK + (r - co * KK))] : 0.f;
    // (simplify: v = co < C4 ? w[r] : 0 — since layout [co][kk] == source [co][ci][k])
    v = (co < C4) ? w[r] : 0.f;
    o[i] = f2bf(v);
}

// ---------------- conv1d k=4 s=2 pad(1,1) via MFMA ----------------
// MODE 0: gather from (input (B,F,22,3), offset (B,F,22,1))
// MODE 1: packed (B,F,88) input
// MODE 2: packed input, output written as (B,F,22,3) keeping c<3
template<int FIN, int MODE>
__global__ __launch_bounds__(256)
void conv_mfma(const float* __restrict__ xin, const float* __restrict__ xoff,
               const unsigned short* __restrict__ wbf, const float* __restrict__ bias,
               float* __restrict__ yout)
{
    constexpr int FOUT  = FIN / 2;
    constexpr int MT    = 128;            // output frames per block
    constexpr int NTILE = FOUT / MT;
    constexpr int NFR   = 2 * MT + 2;     // 258 input frames
    constexpr int NPAIR = NFR / 2;        // 129 frame-pairs

    __shared__ char Xs[C4 * RSB];         // 46112 B -> 3 blocks/CU

    const int b   = blockIdx.x / NTILE;
    const int fo0 = (blockIdx.x - b * NTILE) * MT;
    const int tid = threadIdx.x;
    const int gf0 = 2 * fo0 - 1;

    // ---- stage X-tile: bf16, transposed [ci][frame], frame-pairs packed as u32 ----
    for (int idx = tid; idx < NPAIR * C4; idx += 256) {
        const int lfp = idx / C4;
        const int ci  = idx - lfp * C4;
        const int gf  = gf0 + 2 * lfp;
        float v0 = 0.f, v1 = 0.f;
        if (MODE == 0) {
            const int j = ci >> 2, c = ci & 3;
            if (c < 3) {
                if ((unsigned)gf       < (unsigned)FIN) v0 = xin[((size_t)(b * FIN + gf)     * Jn + j) * 3 + c];
                if ((unsigned)(gf + 1) < (unsigned)FIN) v1 = xin[((size_t)(b * FIN + gf + 1) * Jn + j) * 3 + c];
            } else {
                if ((unsigned)gf       < (unsigned)FIN) v0 = xoff[(size_t)(b * FIN + gf)     * Jn + j];
                if ((unsigned)(gf + 1) < (unsigned)FIN) v1 = xoff[(size_t)(b * FIN + gf + 1) * Jn + j];
            }
        } else {
            if ((unsigned)gf       < (unsigned)FIN) v0 = xin[(size_t)(b * FIN + gf)     * C4 + ci];
            if ((unsigned)(gf + 1) < (unsigned)FIN) v1 = xin[(size_t)(b * FIN + gf + 1) * C4 + ci];
        }
        const unsigned pk = (unsigned)f2bf(v0) | ((unsigned)f2bf(v1) << 16);
        *reinterpret_cast<unsigned*>(&Xs[ci * RSB + lfp * 4]) = pk;
    }
    __syncthreads();

    // ---- K-loop: 11 K-tiles of 32; wave computes 32 rows x 96 cols ----
    const int wid = tid >> 6, lane = tid & 63;
    const int l15 = lane & 15, h = lane >> 4;
    const int mb  = wid * 32;

    floatx4 acc[2][6];
#pragma unroll
    for (int mi = 0; mi < 2; ++mi)
#pragma unroll
        for (int nt = 0; nt < 6; ++nt)
            acc[mi][nt] = (floatx4){0.f, 0.f, 0.f, 0.f};

    const int dmBase = mb + l15;                         // row within tile set
    const unsigned short* wb = wbf + (size_t)l15 * KK + h * 8;

#pragma unroll 2
    for (int kt = 0; kt < 11; ++kt) {
        // A fragments: rows dm, k = kt*32 + h*8 + j ; (ci0, ci0+1) x 4 taps
        const int ci0 = kt * 8 + 2 * h;
        const char* ab = &Xs[ci0 * RSB + 4 * dmBase];
        short8 afr[2];
#pragma unroll
        for (int mi = 0; mi < 2; ++mi) {
            union { unsigned u[4]; short8 v; } t;
            t.u[0] = *reinterpret_cast<const unsigned*>(ab + mi * 64);
            t.u[1] = *reinterpret_cast<const unsigned*>(ab + mi * 64 + 4);
            t.u[2] = *reinterpret_cast<const unsigned*>(ab + mi * 64 + RSB);
            t.u[3] = *reinterpret_cast<const unsigned*>(ab + mi * 64 + RSB + 4);
            afr[mi] = t.v;
        }
        // B fragments: 16B contiguous from global bf16 weights (L2-resident)
        short8 bfr[6];
#pragma unroll
        for (int nt = 0; nt < 6; ++nt)
            bfr[nt] = *reinterpret_cast<const short8*>(wb + (size_t)nt * 16 * KK + kt * 32);
#pragma unroll
        for (int mi = 0; mi < 2; ++mi)
#pragma unroll
            for (int nt = 0; nt < 6; ++nt)
                acc[mi][nt] = __builtin_amdgcn_mfma_f32_16x16x32_bf16(
                    afr[mi], bfr[nt], acc[mi][nt], 0, 0, 0);
    }

    // ---- epilogue: D layout col = lane&15, row = 4*(lane>>4) + reg ----
#pragma unroll
    for (int nt = 0; nt < 6; ++nt) {
        const int co = nt * 16 + l15;
        if (co >= C4) continue;
        const float bi = bias[co];
#pragma unroll
        for (int mi = 0; mi < 2; ++mi) {
            const int m0 = fo0 + mb + mi * 16 + h * 4;
#pragma unroll
            for (int r = 0; r < 4; ++r) {
                const float val = acc[mi][nt][r] + bi;
                const int m = m0 + r;
                if (MODE < 2) {
                    yout[(size_t)(b * FOUT + m) * C4 + co] = val;
                } else {
                    const int j = co >> 2, c = co & 3;
                    if (c < 3)
                        yout[((size_t)(b * FOUT + m) * Jn + j) * 3 + c] = val;
                }
            }
        }
    }
}

// ---------------- graph block (fp32, per (b,f) row, in-place safe) ----------------
struct GW {
    const float *n2n_w, *n2n_b, *e2n_we, *e2n_wn, *e2n_b;
    const float *n2e_wn, *n2e_we, *n2e_b, *lin_w, *lin_b;
};

__global__ __launch_bounds__(256)
void graph_kernel(const float* x, float* y, GW g, int nrow)
{
    const int row = blockIdx.x * 256 + threadIdx.x;
    if (row >= nrow) return;

    const float4* xr = reinterpret_cast<const float4*>(x) + (size_t)row * Jn;
    float4*       yr = reinterpret_cast<float4*>(y) + (size_t)row * Jn;

    float nd[Jn][3], ed[Jn];
#pragma unroll
    for (int j = 0; j < Jn; ++j) {
        const float4 t = xr[j];
        nd[j][0] = t.x; nd[j][1] = t.y; nd[j][2] = t.z; ed[j] = t.w;
    }

    float n2n[9], n2nb[3], e2we[3], e2wn[9], e2nb[3], newn[3], lin[18], linb[3];
#pragma unroll
    for (int i = 0; i < 9;  ++i) n2n[i]  = g.n2n_w[i];
#pragma unroll
    for (int i = 0; i < 3;  ++i) n2nb[i] = g.n2n_b[i];
#pragma unroll
    for (int i = 0; i < 3;  ++i) e2we[i] = g.e2n_we[i];
#pragma unroll
    for (int i = 0; i < 9;  ++i) e2wn[i] = g.e2n_wn[i];
#pragma unroll
    for (int i = 0; i < 3;  ++i) e2nb[i] = g.e2n_b[i];
#pragma unroll
    for (int i = 0; i < 3;  ++i) newn[i] = g.n2e_wn[i];
    const float newe = g.n2e_we[0];
    const float neb  = g.n2e_b[0];
#pragma unroll
    for (int i = 0; i < 18; ++i) lin[i]  = g.lin_w[i];
#pragma unroll
    for (int i = 0; i < 3;  ++i) linb[i] = g.lin_b[i];

#pragma unroll
    for (int i = 0; i < Jn; ++i) {
        float an0 = 0.f, an1 = 0.f, an2 = 0.f, ae = 0.f;
#pragma unroll
        for (int j = 1; j < Jn; ++j) {
            if (TOPc[j] == i) {
                an0 += nd[j][0]; an1 += nd[j][1]; an2 += nd[j][2]; ae += ed[j];
            }
        }
        float f1[3], f2[3];
#pragma unroll
        for (int c = 0; c < 3; ++c) {
            f1[c] = an0 * n2n[0 * 3 + c] + an1 * n2n[1 * 3 + c] + an2 * n2n[2 * 3 + c] + n2nb[c];
            f2[c] = ae * e2we[c]
                  + nd[i][0] * e2wn[0 * 3 + c] + nd[i][1] * e2wn[1 * 3 + c] + nd[i][2] * e2wn[2 * 3 + c]
                  + e2nb[c];
        }
        float p0 = 0.f, p1 = 0.f, p2 = 0.f;
        if (i > 0) { const int p = TOPc[i]; p0 = nd[p][0]; p1 = nd[p][1]; p2 = nd[p][2]; }
        const float ne = p0 * newn[0] + p1 * newn[1] + p2 * newn[2] + ed[i] * newe + neb;

        float4 o;
        o.x = f1[0] * lin[0] + f1[1] * lin[3] + f1[2] * lin[6]
            + f2[0] * lin[9] + f2[1] * lin[12] + f2[2] * lin[15] + linb[0];
        o.y = f1[0] * lin[1] + f1[1] * lin[4] + f1[2] * lin[7]
            + f2[0] * lin[10] + f2[1] * lin[13] + f2[2] * lin[16] + linb[1];
        o.z = f1[0] * lin[2] + f1[1] * lin[5] + f1[2] * lin[8]
            + f2[0] * lin[11] + f2[1] * lin[14] + f2[2] * lin[17] + linb[2];
        o.w = ne;
        yr[i] = o;
    }
}

extern "C" void kernel_launch(void* const* d_in, const int* in_sizes, int n_in,
                              void* d_out, int out_size, void* d_ws, size_t ws_size,
                              hipStream_t stream)
{
    (void)n_in; (void)out_size; (void)ws_size;

    const float* input  = (const float*)d_in[0];
    const float* offset = (const float*)d_in[1];
    const float* c1w = (const float*)d_in[2]; const float* c1b = (const float*)d_in[3];
    const float* c2w = (const float*)d_in[4]; const float* c2b = (const float*)d_in[5];
    const float* c3w = (const float*)d_in[6]; const float* c3b = (const float*)d_in[7];

    GW g1 { (const float*)d_in[8],  (const float*)d_in[9],  (const float*)d_in[10],
            (const float*)d_in[11], (const float*)d_in[12], (const float*)d_in[13],
            (const float*)d_in[14], (const float*)d_in[15], (const float*)d_in[16],
            (const float*)d_in[17] };
    GW g2 { (const float*)d_in[18], (const float*)d_in[19], (const float*)d_in[20],
            (const float*)d_in[21], (const float*)d_in[22], (const float*)d_in[23],
            (const float*)d_in[24], (const float*)d_in[25], (const float*)d_in[26],
            (const float*)d_in[27] };

    const int B = in_sizes[0] / (2048 * Jn * 3);   // 128

    float* ws1 = (float*)d_ws;                               // (B,1024,88) f32
    float* ws2 = ws1 + (size_t)B * 1024 * C4;                // (B, 512,88) f32
    unsigned short* wbf = (unsigned short*)(ws2 + (size_t)B * 512 * C4);  // 3 x [96][352] bf16
    float* out = (float*)d_out;                              // (B,256,22,3)

    // pre-cast conv weights to bf16 (padded to 96 rows)
    {
        const int tot = 3 * NPAD * KK;
        prep_weights<<<(tot + 255) / 256, 256, 0, stream>>>(c1w, c2w, c3w, wbf);
    }

    conv_mfma<2048, 0><<<B * 8, 256, 0, stream>>>(input, offset, wbf,                c1b, ws1);
    graph_kernel<<<(B * 1024 + 255) / 256, 256, 0, stream>>>(ws1, ws1, g1, B * 1024);
    conv_mfma<1024, 1><<<B * 4, 256, 0, stream>>>(ws1, nullptr, wbf + 1 * NPAD * KK, c2b, ws2);
    graph_kernel<<<(B * 512 + 255) / 256, 256, 0, stream>>>(ws2, ws2, g2, B * 512);
    conv_mfma< 512, 2><<<B * 2, 256, 0, stream>>>(ws2, nullptr, wbf + 2 * NPAD * KK, c3b, out);
}

// Round 3
// 84.065 us; speedup vs baseline: 6.4364x; 2.1873x over previous
//
#include <hip/hip_runtime.h>

// Encoder_29661044146233 — round 3:
//  * tap-major im2col K-order  -> LDS X-tile needs NO transpose (rows = frames)
//  * branchless uniform staging (conv1 from f32 input/offset; conv2/3 from packed bf16)
//  * graph blocks FUSED into conv epilogue via LDS Ytile bounce -> bf16 packed output
//  * MT=64, 27 KB LDS, waves partitioned 2(M-half) x 2(N-half)

static constexpr int Jn   = 22;
static constexpr int C4   = 88;     // 22 joints * 4 channels
static constexpr int KK   = 352;    // 4 taps * 88 ci   (tap-major: k = tap*88 + ci)
static constexpr int NPAD = 96;     // padded out-channels (6 tiles of 16)
static constexpr int LROW = 104;    // LDS X row stride in ushorts (208 B)
static constexpr int YROW = 101;    // Ytile row stride in floats (404 B)
static constexpr int NFR  = 130;    // input frames per block (2*64 + 2 halo)

typedef __attribute__((ext_vector_type(8))) short    short8;
typedef __attribute__((ext_vector_type(4))) float    floatx4;
typedef __attribute__((ext_vector_type(4))) unsigned uintx4;

__device__ constexpr int TOPc[Jn] = {0,0,1,2,3,4,0,6,7,8,0,10,11,12,12,14,15,16,12,18,19,20};

__device__ __forceinline__ unsigned short f2bf(float f) {
    unsigned u = __builtin_bit_cast(unsigned, f);
    unsigned r = (u + 0x7FFFu + ((u >> 16) & 1u)) >> 16;
    return (unsigned short)r;
}

struct GW {
    const float *n2n_w, *n2n_b, *e2n_we, *e2n_wn, *e2n_b;
    const float *n2e_wn, *n2e_we, *n2e_b, *lin_w, *lin_b;
};

// ---- weight prep: fp32 (88,88,4) [co][ci][tap] -> bf16 [96][352] tap-major, zero-padded ----
__global__ __launch_bounds__(256)
void prep_weights(const float* __restrict__ w1, const float* __restrict__ w2,
                  const float* __restrict__ w3, unsigned short* __restrict__ o)
{
    const int i = blockIdx.x * 256 + threadIdx.x;
    constexpr int per = NPAD * KK;
    if (i >= 3 * per) return;
    const int s  = i / per, r = i - s * per;
    const int co = r / KK, k = r - co * KK;
    const int tap = k / C4, ci = k - tap * C4;
    const float* w = (s == 0) ? w1 : (s == 1) ? w2 : w3;
    const float v = (co < C4) ? w[((size_t)co * C4 + ci) * 4 + tap] : 0.f;
    o[i] = f2bf(v);
}

// ---------------- fused conv1d(k=4,s=2,pad 1,1) [+ graph block] ----------------
// INM 0: stage from f32 (input (B,F,22,3), offset (B,F,22,1));  INM 1: from packed bf16 (B,F,88)
// OUTM 0: graph-block fused epilogue -> packed bf16 (B,FOUT,88)
// OUTM 1: direct f32 (B,FOUT,22,3) output, c<3 only
template<int FIN, int INM, int OUTM>
__global__ __launch_bounds__(256, 4)
void conv_fused(const float* __restrict__ xf, const float* __restrict__ xoff,
                const unsigned short* __restrict__ xbf,
                const unsigned short* __restrict__ wbf, const float* __restrict__ bias,
                void* __restrict__ yout, GW g)
{
    constexpr int FOUT   = FIN / 2;
    constexpr int NTILE  = FOUT / 64;
    __shared__ __align__(16) unsigned char smem[NFR * LROW * 2];   // 27040 B (>= Ytile 25856 B)
    unsigned short* Xs = reinterpret_cast<unsigned short*>(smem);
    float*          Yt = reinterpret_cast<float*>(smem);

    const int tid = threadIdx.x;
    const int b   = blockIdx.x / NTILE;
    const int fo0 = (blockIdx.x - b * NTILE) * 64;
    const int gf0 = 2 * fo0 - 1;

    // ---------------- stage X tile (rows = input frames, 88 bf16 each) ----------------
    if (INM == 0) {
        // input part: 66 floats/frame -> ci = p + p/3  (= 4j+c, c<3)
        for (int idx = tid; idx < NFR * 66; idx += 256) {
            const int lf = idx / 66, p = idx - lf * 66;
            const int gf = gf0 + lf;
            const int gfc = min(max(gf, 0), FIN - 1);
            float v = xf[((size_t)b * FIN + gfc) * 66 + p];
            v = (gf == gfc) ? v : 0.f;
            Xs[lf * LROW + p + p / 3] = f2bf(v);
        }
        // offset part: 22 floats/frame -> ci = 4j+3
        for (int idx = tid; idx < NFR * 22; idx += 256) {
            const int lf = idx / 22, j = idx - lf * 22;
            const int gf = gf0 + lf;
            const int gfc = min(max(gf, 0), FIN - 1);
            float v = xoff[((size_t)b * FIN + gfc) * 22 + j];
            v = (gf == gfc) ? v : 0.f;
            Xs[lf * LROW + 4 * j + 3] = f2bf(v);
        }
    } else {
        // packed bf16 rows: 11 x 16B chunks per frame, fully coalesced
        const uintx4 zero = {0u, 0u, 0u, 0u};
        for (int idx = tid; idx < NFR * 11; idx += 256) {
            const int lf = idx / 11, q = idx - lf * 11;
            const int gf = gf0 + lf;
            const int gfc = min(max(gf, 0), FIN - 1);
            uintx4 v = *reinterpret_cast<const uintx4*>(xbf + ((size_t)b * FIN + gfc) * C4 + q * 8);
            v = (gf == gfc) ? v : zero;
            *reinterpret_cast<uintx4*>(Xs + lf * LROW + q * 8) = v;
        }
    }
    __syncthreads();

    // ---------------- K-loop: wave = (m-half 32 rows) x (n-half 48 cols) ----------------
    const int wid = tid >> 6, lane = tid & 63;
    const int l15 = lane & 15, h = lane >> 4;
    const int mhalf = wid >> 1, nhalf = wid & 1;

    floatx4 acc[2][3];
#pragma unroll
    for (int mt = 0; mt < 2; ++mt)
#pragma unroll
        for (int nti = 0; nti < 3; ++nti)
            acc[mt][nti] = (floatx4){0.f, 0.f, 0.f, 0.f};

    const unsigned short* wb = wbf + (size_t)(nhalf * 48 + l15) * KK;

#pragma unroll
    for (int kt = 0; kt < 11; ++kt) {
        const int q   = 4 * kt + h;            // [0,44)
        const int tap = (unsigned)q / 11u;
        const int ci0 = 8 * (q - 11 * tap);
        const int lfb = 2 * l15 + tap;         // + 64*mhalf + 32*mt

        short8 afr[2];
#pragma unroll
        for (int mt = 0; mt < 2; ++mt)
            afr[mt] = *reinterpret_cast<const short8*>(
                Xs + (mhalf * 64 + mt * 32 + lfb) * LROW + ci0);

        short8 bfr[3];
#pragma unroll
        for (int nti = 0; nti < 3; ++nti)
            bfr[nti] = *reinterpret_cast<const short8*>(wb + (size_t)nti * 16 * KK + kt * 32 + 8 * h);

#pragma unroll
        for (int mt = 0; mt < 2; ++mt)
#pragma unroll
            for (int nti = 0; nti < 3; ++nti)
                acc[mt][nti] = __builtin_amdgcn_mfma_f32_16x16x32_bf16(
                    afr[mt], bfr[nti], acc[mt][nti], 0, 0, 0);
    }

    // ---------------- epilogue ----------------
    if (OUTM == 1) {
        // direct f32 (B,FOUT,22,3)
        float* yo = reinterpret_cast<float*>(yout);
#pragma unroll
        for (int mt = 0; mt < 2; ++mt)
#pragma unroll
            for (int nti = 0; nti < 3; ++nti) {
                const int co = nhalf * 48 + nti * 16 + l15;
                if (co < C4) {
                    const int j = co >> 2, c = co & 3;
                    if (c < 3) {
                        const float bi = bias[co];
#pragma unroll
                        for (int r = 0; r < 4; ++r) {
                            const int m = fo0 + mhalf * 32 + mt * 16 + 4 * h + r;
                            yo[((size_t)(b * FOUT + m) * Jn + j) * 3 + c] = acc[mt][nti][r] + bi;
                        }
                    }
                }
            }
        return;
    }

    // graph-fused: acc -> LDS Ytile (f32, stride 101)
    __syncthreads();   // all X reads done before overwrite
#pragma unroll
    for (int mt = 0; mt < 2; ++mt)
#pragma unroll
        for (int nti = 0; nti < 3; ++nti) {
            const int co = nhalf * 48 + nti * 16 + l15;
            const float bi = (co < C4) ? bias[co] : 0.f;
#pragma unroll
            for (int r = 0; r < 4; ++r) {
                const int row = mhalf * 32 + mt * 16 + 4 * h + r;
                Yt[row * YROW + co] = acc[mt][nti][r] + bi;
            }
        }
    __syncthreads();

    // graph block: thread = (row = tid&63, joint-group = tid>>6); groups of 6,6,6,4
    {
        const int row = tid & 63, grp = tid >> 6;
        const float* yr = Yt + row * YROW;

        float n2n[9], n2nb[3], e2we[3], e2wn[9], e2nb[3], newn[3], lin[18], linb[3];
#pragma unroll
        for (int i = 0; i < 9;  ++i) n2n[i]  = g.n2n_w[i];
#pragma unroll
        for (int i = 0; i < 3;  ++i) n2nb[i] = g.n2n_b[i];
#pragma unroll
        for (int i = 0; i < 3;  ++i) e2we[i] = g.e2n_we[i];
#pragma unroll
        for (int i = 0; i < 9;  ++i) e2wn[i] = g.e2n_wn[i];
#pragma unroll
        for (int i = 0; i < 3;  ++i) e2nb[i] = g.e2n_b[i];
#pragma unroll
        for (int i = 0; i < 3;  ++i) newn[i] = g.n2e_wn[i];
        const float newe = g.n2e_we[0];
        const float neb  = g.n2e_b[0];
#pragma unroll
        for (int i = 0; i < 18; ++i) lin[i]  = g.lin_w[i];
#pragma unroll
        for (int i = 0; i < 3;  ++i) linb[i] = g.lin_b[i];

        unsigned short* xout = reinterpret_cast<unsigned short*>(yout);
        const size_t orow = ((size_t)b * FOUT + fo0 + row) * C4;

#pragma unroll
        for (int i = 0; i < Jn; ++i) {
            if (i / 6 != grp) continue;      // wave-uniform branch
            float an0 = 0.f, an1 = 0.f, an2 = 0.f, ae = 0.f;
#pragma unroll
            for (int j = 1; j < Jn; ++j) {
                if (TOPc[j] == i) {
                    an0 += yr[4 * j]; an1 += yr[4 * j + 1];
                    an2 += yr[4 * j + 2]; ae += yr[4 * j + 3];
                }
            }
            const float s0 = yr[4 * i], s1 = yr[4 * i + 1], s2 = yr[4 * i + 2], se = yr[4 * i + 3];
            float f1[3], f2[3];
#pragma unroll
            for (int c = 0; c < 3; ++c) {
                f1[c] = an0 * n2n[c] + an1 * n2n[3 + c] + an2 * n2n[6 + c] + n2nb[c];
                f2[c] = ae * e2we[c] + s0 * e2wn[c] + s1 * e2wn[3 + c] + s2 * e2wn[6 + c] + e2nb[c];
            }
            float p0 = 0.f, p1 = 0.f, p2 = 0.f;
            if (i > 0) {
                const int p = TOPc[i];
                p0 = yr[4 * p]; p1 = yr[4 * p + 1]; p2 = yr[4 * p + 2];
            }
            const float ne = p0 * newn[0] + p1 * newn[1] + p2 * newn[2] + se * newe + neb;

            float o[3];
#pragma unroll
            for (int c = 0; c < 3; ++c)
                o[c] = f1[0] * lin[0 + c] + f1[1] * lin[3 + c] + f1[2] * lin[6 + c]
                     + f2[0] * lin[9 + c] + f2[1] * lin[12 + c] + f2[2] * lin[15 + c] + linb[c];

            uint2 pk;
            pk.x = (unsigned)f2bf(o[0]) | ((unsigned)f2bf(o[1]) << 16);
            pk.y = (unsigned)f2bf(o[2]) | ((unsigned)f2bf(ne)   << 16);
            *reinterpret_cast<uint2*>(xout + orow + 4 * i) = pk;
        }
    }
}

extern "C" void kernel_launch(void* const* d_in, const int* in_sizes, int n_in,
                              void* d_out, int out_size, void* d_ws, size_t ws_size,
                              hipStream_t stream)
{
    (void)n_in; (void)out_size; (void)ws_size;

    const float* input  = (const float*)d_in[0];
    const float* offset = (const float*)d_in[1];
    const float* c1w = (const float*)d_in[2]; const float* c1b = (const float*)d_in[3];
    const float* c2w = (const float*)d_in[4]; const float* c2b = (const float*)d_in[5];
    const float* c3w = (const float*)d_in[6]; const float* c3b = (const float*)d_in[7];

    GW g1 { (const float*)d_in[8],  (const float*)d_in[9],  (const float*)d_in[10],
            (const float*)d_in[11], (const float*)d_in[12], (const float*)d_in[13],
            (const float*)d_in[14], (const float*)d_in[15], (const float*)d_in[16],
            (const float*)d_in[17] };
    GW g2 { (const float*)d_in[18], (const float*)d_in[19], (const float*)d_in[20],
            (const float*)d_in[21], (const float*)d_in[22], (const float*)d_in[23],
            (const float*)d_in[24], (const float*)d_in[25], (const float*)d_in[26],
            (const float*)d_in[27] };

    const int B = in_sizes[0] / (2048 * Jn * 3);   // 128

    unsigned short* wbf = (unsigned short*)d_ws;             // 3 x [96][352] bf16 = 198 KB
    unsigned short* X1  = wbf + (size_t)3 * NPAD * KK;       // (B,1024,88) bf16 = 23.1 MB
    unsigned short* X2  = X1 + (size_t)B * 1024 * C4;        // (B, 512,88) bf16 = 11.5 MB

    {
        const int tot = 3 * NPAD * KK;
        prep_weights<<<(tot + 255) / 256, 256, 0, stream>>>(c1w, c2w, c3w, wbf);
    }

    // conv1 + graph1 -> X1 (bf16 packed)
    conv_fused<2048, 0, 0><<<B * 16, 256, 0, stream>>>(input, offset, nullptr,
                                                       wbf, c1b, X1, g1);
    // conv2 + graph2 -> X2 (bf16 packed)
    conv_fused<1024, 1, 0><<<B * 8, 256, 0, stream>>>(nullptr, nullptr, X1,
                                                      wbf + NPAD * KK, c2b, X2, g2);
    // conv3 -> d_out f32 (B,256,22,3)
    conv_fused<512, 1, 1><<<B * 4, 256, 0, stream>>>(nullptr, nullptr, X2,
                                                     wbf + 2 * NPAD * KK, c3b, d_out, g2);
}